// Round 3
// baseline (1044.444 us; speedup 1.0000x reference)
//
#include <hip/hip_runtime.h>
#include <hip/hip_bf16.h>

// N=65536 points, H=256, 4 hidden layers, ReLU MLP -> (psi,p).
// ReLU => piecewise linear => Hessians vanish; f = p_x, g = p_y (RHO=1).
// Pipeline:
//   1) fp32 forward replicating np/BLAS arithmetic BIT-EXACTLY
//      (per-element sequential k-ascending FMA chain, bias added AFTER the
//      GEMM, relu mask = a > 0) -> exact reference masks + p   [VALU fp32]
//   2) per-tangent (x, y) forward-mode chain: fp32 T storage,
//      hi/lo-split fp16 MFMA (fp32-quality GEMM)               [MFMA]
//   3) tiny epilogues: u,v (from Wout col 0), f,g (from Wout col 1)
// Workspace: bufA 64MB | bufB 64MB | masks 5x2MB | Wt_hi 512KB | Wt_lo 512KB

#define NPTS 65536
#define HDIM 256

typedef _Float16 half8_t __attribute__((ext_vector_type(8)));
typedef _Float16 half4_t __attribute__((ext_vector_type(4)));
typedef float floatx4 __attribute__((ext_vector_type(4)));

// ---------------------------------------------------------------- fused fp32 forward (np/BLAS-exact)
// 16 points/block, 256 threads. hT[k][p] floats in LDS (16KB) + W panel (32KB).
// Thread owns 2 points (pgrp) x 8 cols (cgrp). Each output element is a single
// sequential k-ascending fmaf chain starting from 0, bias added after (BLAS
// sgemm microkernel semantics). Writes masks L0..L4 + p output.
__global__ void __launch_bounds__(256) fwd_fused_kernel(
    const float* __restrict__ x, const float* __restrict__ y, const float* __restrict__ t,
    const float* __restrict__ Win, const float* __restrict__ b_in,
    const float* __restrict__ Wh, const float* __restrict__ b_h,
    const float* __restrict__ Wout, const float* __restrict__ b_out,
    unsigned char* __restrict__ masks, float* __restrict__ out) {
  __shared__ float hT[256 * 16];       // [k][p]
  __shared__ float Wpan[32 * 256];     // [k][c]
  __shared__ float pscr[16][33];

  const int tid = threadIdx.x;
  const int pgrp = tid & 7;            // points 2*pgrp, 2*pgrp+1
  const int cgrp = tid >> 3;           // cols cgrp*8 .. +7
  const int p0 = blockIdx.x * 16;
  const int c0 = cgrp * 8;

  // ---- layer 1: dot = z @ Win (k ascending: x,y,t), then + b_in
#pragma unroll
  for (int j = 0; j < 2; ++j) {
    int pp = 2 * pgrp + j;
    float xv = x[p0 + pp], yv = y[p0 + pp], tv = t[p0 + pp];
    unsigned m = 0;
#pragma unroll
    for (int e = 0; e < 8; ++e) {
      int c = c0 + e;
      float dot = fmaf(xv, Win[c], 0.f);
      dot = fmaf(yv, Win[256 + c], dot);
      dot = fmaf(tv, Win[512 + c], dot);
      float a = dot + b_in[c];          // bias AFTER the gemm (np adds b separately)
      bool pos = a > 0.f;
      hT[c * 16 + pp] = pos ? a : 0.f;
      m |= (pos ? 1u : 0u) << e;
    }
    masks[(size_t)(p0 + pp) * 32 + cgrp] = (unsigned char)m;
  }
  __syncthreads();

  // ---- hidden layers: single fp32 accumulator per element, k ascending, fmaf
  for (int l = 0; l < 4; ++l) {
    float acc[2][8] = {};
    for (int kp = 0; kp < 8; ++kp) {
      // stage W panel (32 k x 256 c), fp32
#pragma unroll
      for (int i = 0; i < 8; ++i) {
        int j = tid + 256 * i;
        int krow = j >> 6, cseg = j & 63;
        *(float4*)&Wpan[krow * 256 + cseg * 4] =
            *(const float4*)(Wh + (size_t)l * 65536 + (size_t)(kp * 32 + krow) * 256 + cseg * 4);
      }
      __syncthreads();
#pragma unroll 8
      for (int k = 0; k < 32; ++k) {
        int kk = kp * 32 + k;
        float2 h2 = *(const float2*)&hT[kk * 16 + 2 * pgrp];
        float4 w0 = *(const float4*)&Wpan[k * 256 + c0];
        float4 w1 = *(const float4*)&Wpan[k * 256 + c0 + 4];
        float wv[8] = {w0.x, w0.y, w0.z, w0.w, w1.x, w1.y, w1.z, w1.w};
#pragma unroll
        for (int e = 0; e < 8; ++e) {
          acc[0][e] = fmaf(h2.x, wv[e], acc[0][e]);
          acc[1][e] = fmaf(h2.y, wv[e], acc[1][e]);
        }
      }
      __syncthreads();
    }
    // epilogue: + bias (after), relu, mask bits, write back into hT
#pragma unroll
    for (int j = 0; j < 2; ++j) {
      int pp = 2 * pgrp + j;
      unsigned m = 0;
#pragma unroll
      for (int e = 0; e < 8; ++e) {
        int c = c0 + e;
        float a = acc[j][e] + b_h[l * 256 + c];
        bool pos = a > 0.f;
        hT[c * 16 + pp] = pos ? a : 0.f;
        m |= (pos ? 1u : 0u) << e;
      }
      masks[((size_t)(l + 1) * NPTS + (p0 + pp)) * 32 + cgrp] = (unsigned char)m;
    }
    __syncthreads();
  }

  // ---- p = h5 . Wout[:,1] + b_out[1]  (value-only output; order-insensitive
  //      at bf16 comparison granularity, so a parallel reduction is fine)
#pragma unroll
  for (int j = 0; j < 2; ++j) {
    int pp = 2 * pgrp + j;
    float s = 0.f;
#pragma unroll
    for (int e = 0; e < 8; ++e) {
      int c = c0 + e;
      s = fmaf(hT[c * 16 + pp], Wout[2 * c + 1], s);
    }
    pscr[pp][cgrp] = s;
  }
  __syncthreads();
  if (tid < 16) {
    float s = 0.f;
    for (int g = 0; g < 32; ++g) s += pscr[tid][g];
    out[2 * NPTS + p0 + tid] = s + b_out[1];
  }
}

// ---------------------------------------------------------------- prep: Wh fp32 [l][k][n] -> hi/lo f16 [l][n][k]
__global__ void __launch_bounds__(256) prep_weights_kernel(
    const float* __restrict__ Wh, _Float16* __restrict__ Whi, _Float16* __restrict__ Wlo) {
  int i = blockIdx.x * 256 + threadIdx.x;   // 0..262143
  int l = i >> 16;
  int rem = i & 65535;
  int k = rem >> 8, n = rem & 255;
  float w = Wh[i];
  _Float16 hi = (_Float16)w;
  _Float16 lo = (_Float16)((w - (float)hi) * 2048.f);
  size_t o = (size_t)(l << 16) + n * 256 + k;
  Whi[o] = hi;
  Wlo[o] = lo;
}

// ---------------------------------------------------------------- tangent init (fp32): T1 = mask1 .* Win-row
__global__ void __launch_bounds__(256) tangent_init_kernel(
    const float* __restrict__ WinRow, const unsigned char* __restrict__ mask1,
    float* __restrict__ T) {
  int p = blockIdx.x, c = threadIdx.x;
  bool m = (mask1[(size_t)p * 32 + (c >> 3)] >> (c & 7)) & 1;
  T[(size_t)p * 256 + c] = m ? WinRow[c] : 0.f;
}

// ---------------------------------------------------------------- tangent layer: Tout = (Tin @ W) .* mask
// fp32 in/out; hi/lo split f16 MFMA with second accumulator for 2048-scaled
// cross terms (full fp32-quality product). Block 128x128, 4 waves of 64x64.
// mfma_f32_16x16x32_f16: A[m=lane&15][k=quad*8+j], B[k=quad*8+j][n=lane&15],
//                        D[row=quad*4+reg][col=lane&15]
__global__ void __launch_bounds__(256, 2) tangent_gemm_kernel(
    const float* __restrict__ Tin,
    const _Float16* __restrict__ Whi, const _Float16* __restrict__ Wlo,  // [n][k]
    const unsigned int* __restrict__ maskDw,                             // [NPTS][8]
    float* __restrict__ Tout) {
  constexpr int SK = 72;  // lds row stride (halves)
  __shared__ alignas(16) _Float16 Ahi[128 * SK];
  __shared__ alignas(16) _Float16 Alo[128 * SK];
  __shared__ alignas(16) _Float16 Bhi[128 * SK];
  __shared__ alignas(16) _Float16 Blo[128 * SK];
  __shared__ unsigned int smask[128 * 8];

  const int tid = threadIdx.x;
  const int cb = blockIdx.x;   // 0..1
  const int rb = blockIdx.y;   // 0..511
  const int lane = tid & 63, wave = tid >> 6;
  const int wm = wave & 1, wn = wave >> 1;
  const int l15 = lane & 15, quad = lane >> 4;
  const int p0 = rb * 128;

#pragma unroll
  for (int i = 0; i < 4; ++i) {
    int idx = tid + 256 * i;
    smask[idx] = maskDw[(size_t)p0 * 8 + idx];
  }

  floatx4 acc1[4][4] = {};
  floatx4 acc2[4][4] = {};

  for (int kp = 0; kp < 4; ++kp) {
    __syncthreads();
    // stage A: fp32 -> hi/lo f16 (128 rows x 64 k)
#pragma unroll
    for (int i = 0; i < 8; ++i) {
      int j = tid + 256 * i;          // 0..2047 float4 segs
      int row = j >> 4, seg = j & 15;
      float4 v = *(const float4*)(Tin + (size_t)(p0 + row) * 256 + kp * 64 + seg * 4);
      half4_t h, lo;
      h[0] = (_Float16)v.x; h[1] = (_Float16)v.y; h[2] = (_Float16)v.z; h[3] = (_Float16)v.w;
      lo[0] = (_Float16)((v.x - (float)h[0]) * 2048.f);
      lo[1] = (_Float16)((v.y - (float)h[1]) * 2048.f);
      lo[2] = (_Float16)((v.z - (float)h[2]) * 2048.f);
      lo[3] = (_Float16)((v.w - (float)h[3]) * 2048.f);
      *(half4_t*)&Ahi[row * SK + seg * 4] = h;
      *(half4_t*)&Alo[row * SK + seg * 4] = lo;
    }
    // stage B: hi/lo f16 direct (128 n-rows x 64 k)
#pragma unroll
    for (int i = 0; i < 4; ++i) {
      int j = tid + 256 * i;          // 0..1023 half8 segs
      int row = j >> 3, seg = j & 7;
      *(half8_t*)&Bhi[row * SK + seg * 8] =
          *(const half8_t*)(Whi + (size_t)(cb * 128 + row) * 256 + kp * 64 + seg * 8);
      *(half8_t*)&Blo[row * SK + seg * 8] =
          *(const half8_t*)(Wlo + (size_t)(cb * 128 + row) * 256 + kp * 64 + seg * 8);
    }
    __syncthreads();
#pragma unroll
    for (int ks = 0; ks < 2; ++ks) {
      half8_t ah[4], al[4], bh[4], bl[4];
#pragma unroll
      for (int ti = 0; ti < 4; ++ti) {
        int r = (wm * 64 + ti * 16 + l15) * SK + ks * 32 + quad * 8;
        ah[ti] = *(const half8_t*)&Ahi[r];
        al[ti] = *(const half8_t*)&Alo[r];
      }
#pragma unroll
      for (int tj = 0; tj < 4; ++tj) {
        int r = (wn * 64 + tj * 16 + l15) * SK + ks * 32 + quad * 8;
        bh[tj] = *(const half8_t*)&Bhi[r];
        bl[tj] = *(const half8_t*)&Blo[r];
      }
#pragma unroll
      for (int ti = 0; ti < 4; ++ti)
#pragma unroll
        for (int tj = 0; tj < 4; ++tj) {
          acc1[ti][tj] = __builtin_amdgcn_mfma_f32_16x16x32_f16(ah[ti], bh[tj], acc1[ti][tj], 0, 0, 0);
          acc2[ti][tj] = __builtin_amdgcn_mfma_f32_16x16x32_f16(al[ti], bh[tj], acc2[ti][tj], 0, 0, 0);
          acc2[ti][tj] = __builtin_amdgcn_mfma_f32_16x16x32_f16(ah[ti], bl[tj], acc2[ti][tj], 0, 0, 0);
        }
    }
  }

  // epilogue: combine accs, mask-gate, fp32 store
#pragma unroll
  for (int ti = 0; ti < 4; ++ti) {
#pragma unroll
    for (int r = 0; r < 4; ++r) {
      int rloc = wm * 64 + ti * 16 + quad * 4 + r;
      size_t R = (size_t)p0 + rloc;
#pragma unroll
      for (int tj = 0; tj < 4; ++tj) {
        int C = cb * 128 + wn * 64 + tj * 16 + l15;
        float v = acc1[ti][tj][r] + acc2[ti][tj][r] * (1.f / 2048.f);
        unsigned int dw = smask[rloc * 8 + (C >> 5)];
        Tout[R * 256 + C] = ((dw >> (C & 31)) & 1u) ? v : 0.f;
      }
    }
  }
}

// ---------------------------------------------------------------- finalize one tangent: two dots with Wout cols
__global__ void __launch_bounds__(256) finalize_pass_kernel(
    const float* __restrict__ T5, const float* __restrict__ Wout,
    float* __restrict__ out, float sign0, int off0, int off1) {
  const int lane = threadIdx.x & 63;
  const int wave = threadIdx.x >> 6;
  const int p = blockIdx.x * 4 + wave;
  float4 h = *(const float4*)(T5 + (size_t)p * 256 + lane * 4);
  float4 wA = *(const float4*)(Wout + lane * 8);      // (W[c][0],W[c][1],W[c+1][0],W[c+1][1])
  float4 wB = *(const float4*)(Wout + lane * 8 + 4);
  float s0 = h.x * wA.x + h.y * wA.z + h.z * wB.x + h.w * wB.z;  // . Wout[:,0]
  float s1 = h.x * wA.y + h.y * wA.w + h.z * wB.y + h.w * wB.w;  // . Wout[:,1]
#pragma unroll
  for (int off = 1; off < 64; off <<= 1) {
    s0 += __shfl_xor(s0, off);
    s1 += __shfl_xor(s1, off);
  }
  if (lane == 0) {
    out[off0 + p] = sign0 * s0;
    out[off1 + p] = s1;
  }
}

// ---------------------------------------------------------------- launch
extern "C" void kernel_launch(void* const* d_in, const int* in_sizes, int n_in,
                              void* d_out, int out_size, void* d_ws, size_t ws_size,
                              hipStream_t stream) {
  const float* x = (const float*)d_in[0];
  const float* y = (const float*)d_in[1];
  const float* t = (const float*)d_in[2];
  const float* Win = (const float*)d_in[3];
  const float* b_in = (const float*)d_in[4];
  const float* Wh = (const float*)d_in[5];
  const float* b_h = (const float*)d_in[6];
  const float* Wout = (const float*)d_in[7];
  const float* b_out = (const float*)d_in[8];
  float* out = (float*)d_out;

  char* ws = (char*)d_ws;
  constexpr size_t BUF_SZ = (size_t)NPTS * 256 * 4;   // 64 MB fp32 tangent buffer
  constexpr size_t MASK_SZ = (size_t)NPTS * 32;       // 2 MB per layer
  float* bufA = (float*)ws;
  float* bufB = (float*)(ws + BUF_SZ);
  unsigned char* masks = (unsigned char*)(ws + 2 * BUF_SZ);
  _Float16* Wt_hi = (_Float16*)(ws + 2 * BUF_SZ + 5 * MASK_SZ);
  _Float16* Wt_lo = Wt_hi + 4 * 65536;

  // fp32 np-exact forward: masks L0..L4 + p
  fwd_fused_kernel<<<NPTS / 16, 256, 0, stream>>>(
      x, y, t, Win, b_in, Wh, b_h, Wout, b_out, masks, out);

  prep_weights_kernel<<<1024, 256, 0, stream>>>(Wh, Wt_hi, Wt_lo);

  // two tangent passes: s=0 -> x-tangent (v, f), s=1 -> y-tangent (u, g)
  for (int s = 0; s < 2; ++s) {
    tangent_init_kernel<<<NPTS, 256, 0, stream>>>(Win + s * 256, masks, bufA);
    float* Tin = bufA;
    float* To = bufB;
    dim3 ggrid(2, 512);
    for (int l = 0; l < 4; ++l) {
      tangent_gemm_kernel<<<ggrid, 256, 0, stream>>>(
          Tin, Wt_hi + (size_t)l * 65536, Wt_lo + (size_t)l * 65536,
          (const unsigned int*)(masks + (size_t)(l + 1) * MASK_SZ), To);
      float* tmp = Tin; Tin = To; To = tmp;
    }
    if (s == 0)
      finalize_pass_kernel<<<NPTS / 4, 256, 0, stream>>>(Tin, Wout, out, -1.f, NPTS, 3 * NPTS);
    else
      finalize_pass_kernel<<<NPTS / 4, 256, 0, stream>>>(Tin, Wout, out, 1.f, 0, 4 * NPTS);
  }
}